// Round 2
// baseline (546.526 us; speedup 1.0000x reference)
//
#include <hip/hip_runtime.h>
#include <math.h>

// Problem constants (fixed by setup_inputs)
constexpr int B = 16, C = 64, H = 256, W = 256;
constexpr int HW = H * W;            // 65536
constexpr int BHW = B * HW;          // 1048576
constexpr int K = 11, P = 5;         // 11x11 gaussian, pad 5
#define EPS 1e-6f

// ---------------------------------------------------------------------------
// Kernel 1: channel reduction.  For each pixel (b,h,w):
//   sxx = sum_c x^2, sxy = sum_c x*y, syy = sum_c y^2
// Each thread owns 4 consecutive w-pixels (float4 loads, 16B/lane).
// Reads 512 MB (structural floor).  v2: explicit 8-deep load batching so
// each wave keeps 16 float4 loads (16 KB) in flight — v1's 36 VGPRs showed
// the compiler serialized load->wait->FMA pairs (3 TB/s plateau).
// ---------------------------------------------------------------------------
__global__ __launch_bounds__(256) void k_reduce(
    const float* __restrict__ x, const float* __restrict__ y,
    float* __restrict__ s /* [3][B][HW] */)
{
    const int GPI = HW / 4;                       // float4 groups per plane = 16384
    int idx = blockIdx.x * 256 + threadIdx.x;     // [0, B*GPI)
    int b = idx >> 14;                            // idx / GPI
    int g = idx & (GPI - 1);

    const float4* x4 = (const float4*)x + (size_t)b * C * GPI + g;
    const float4* y4 = (const float4*)y + (size_t)b * C * GPI + g;

    float4 axx = make_float4(0.f, 0.f, 0.f, 0.f);
    float4 axy = axx, ayy = axx;

    float4 xv[8], yv[8];
#pragma unroll 1
    for (int c = 0; c < C; c += 8) {
#pragma unroll
        for (int u = 0; u < 8; ++u) {
            xv[u] = x4[u * GPI];
            yv[u] = y4[u * GPI];
        }
        x4 += 8 * GPI;
        y4 += 8 * GPI;
#pragma unroll
        for (int u = 0; u < 8; ++u) {
            axx.x += xv[u].x * xv[u].x; axx.y += xv[u].y * xv[u].y;
            axx.z += xv[u].z * xv[u].z; axx.w += xv[u].w * xv[u].w;
            axy.x += xv[u].x * yv[u].x; axy.y += xv[u].y * yv[u].y;
            axy.z += xv[u].z * yv[u].z; axy.w += xv[u].w * yv[u].w;
            ayy.x += yv[u].x * yv[u].x; ayy.y += yv[u].y * yv[u].y;
            ayy.z += yv[u].z * yv[u].z; ayy.w += yv[u].w * yv[u].w;
        }
    }

    float4* s4 = (float4*)s;
    int o = idx;                                   // == b*GPI + g
    s4[o]                 = axx;
    s4[(BHW / 4) + o]     = axy;
    s4[2 * (BHW / 4) + o] = ayy;
}

// ---------------------------------------------------------------------------
// The 11x11 gaussian is rank-1:  g2d[i][j] = (g[5][j]/sqrt(g[5][5])) *
//                                            (g[i][5]/sqrt(g[5][5]))
// Kernel 2 (fused): per-block row-band separable blur + cosine combine.
// Block = 256 threads (one thread per column), R=8 output rows per block.
// LDS: 18 hblurred rows x 3 maps (55 KB) + 1 raw row staging (3 KB).
// ---------------------------------------------------------------------------
constexpr int R = 8;
constexpr int BAND = R + 2 * P;      // 18 input rows per band

__global__ __launch_bounds__(256) void k_blur_combine(
    const float* __restrict__ s, const float* __restrict__ gauss,
    float* __restrict__ out /* [B][HW] */)
{
    __shared__ float hb[BAND * 3 * W];   // hblurred rows, [r][map][col]
    __shared__ float raw[3 * W];         // raw row staging, [map][col]

    const int t = threadIdx.x;           // column 0..255
    const int blk = blockIdx.x;
    const int b = blk >> 5;              // / (H/R) = /32
    const int band = blk & 31;
    const int r0 = band * R;             // first output row of this block

    const float inv = 1.0f / sqrtf(gauss[5 * K + 5]);
    float wrow[K], wcol[K];
#pragma unroll
    for (int j = 0; j < K; ++j) wrow[j] = gauss[5 * K + j] * inv;
#pragma unroll
    for (int i = 0; i < K; ++i) wcol[i] = gauss[i * K + 5] * inv;

    // Phase 1: horizontal blur of BAND rows into LDS.
    for (int r = 0; r < BAND; ++r) {
        int gr = r0 - P + r;
        bool v = (gr >= 0) && (gr < H);
        int rowoff = b * HW + gr * W + t;
        raw[0 * W + t] = v ? s[rowoff] : 0.f;
        raw[1 * W + t] = v ? s[BHW + rowoff] : 0.f;
        raw[2 * W + t] = v ? s[2 * BHW + rowoff] : 0.f;
        __syncthreads();
        float a0 = 0.f, a1 = 0.f, a2 = 0.f;
#pragma unroll
        for (int j = 0; j < K; ++j) {
            int c = t + j - P;
            if (c >= 0 && c < W) {                 // zero pad (SAME)
                float wj = wrow[j];
                a0 += wj * raw[0 * W + c];
                a1 += wj * raw[1 * W + c];
                a2 += wj * raw[2 * W + c];
            }
        }
        hb[(r * 3 + 0) * W + t] = a0;
        hb[(r * 3 + 1) * W + t] = a1;
        hb[(r * 3 + 2) * W + t] = a2;
        __syncthreads();                           // protect raw for next row
    }

    // Phase 2: vertical blur + cosine combine, R output rows per thread-col.
#pragma unroll
    for (int rr = 0; rr < R; ++rr) {
        float axx = 0.f, axy = 0.f, ayy = 0.f;
#pragma unroll
        for (int i = 0; i < K; ++i) {
            float wi = wcol[i];
            int rb = ((rr + i) * 3) * W + t;
            axx += wi * hb[rb];
            axy += wi * hb[rb + W];
            ayy += wi * hb[rb + 2 * W];
        }
        out[b * HW + (r0 + rr) * W + t] = axy / (sqrtf(axx) * sqrtf(ayy) + EPS);
    }
}

extern "C" void kernel_launch(void* const* d_in, const int* in_sizes, int n_in,
                              void* d_out, int out_size, void* d_ws, size_t ws_size,
                              hipStream_t stream) {
    const float* x     = (const float*)d_in[0];
    const float* y     = (const float*)d_in[1];
    const float* gauss = (const float*)d_in[2];
    float* out = (float*)d_out;

    float* s = (float*)d_ws;        // [3][B][HW]  12 MB scratch

    // K1: 16 * 16384 groups / 256 threads = 1024 blocks
    k_reduce<<<B * (HW / 4) / 256, 256, 0, stream>>>(x, y, s);
    // K2: 16 images * 32 bands = 512 blocks
    k_blur_combine<<<B * (H / R), 256, 0, stream>>>(s, gauss, out);
}